// Round 10
// baseline (96.862 us; speedup 1.0000x reference)
//
#include <hip/hip_runtime.h>
#include <hip/hip_bf16.h>

// MoE adapter: out = x + sum_{e in top2} g_e * (relu(x@Wd[e]+bd[e]) @ Wu[e] + bu[e])
// B=8, L=2048, H=1024, E=8, R=256, top_k=2 (pipeline supports up to 2 slots).
// prep(pool + x->bf16 A-image) -> tiled bf16 weights -> GEMM1 (h, gate-folded) -> GEMM2 (+residual).
// GEMM K-loops use counted-vmcnt two-barrier schedule (loads stay in flight across barriers).

typedef __attribute__((ext_vector_type(8))) short s8v;
typedef __attribute__((ext_vector_type(4))) short s4v;
typedef __attribute__((ext_vector_type(4))) float f4v;

constexpr int Bc = 8, Lc = 2048, Hc = 1024, Ec = 8, Rc = 256;

__device__ __forceinline__ unsigned short f2bf(float f) {
  unsigned int u = __float_as_uint(f);
  u += 0x7fffu + ((u >> 16) & 1u);   // RNE
  return (unsigned short)(u >> 16);
}

typedef __attribute__((address_space(1))) const unsigned int ga_u32;
typedef __attribute__((address_space(3))) unsigned int ls_u32;
__device__ __forceinline__ void gload_lds16(const void* g, void* l) {
  __builtin_amdgcn_global_load_lds((ga_u32*)g, (ls_u32*)l, 16, 0, 0);
}

// ---------------- prep: pool partials + x -> bf16 in gemm1 A-image layout ----------------
// grid (B, 64): block = (b, 32-row chunk), 512 blocks (2/CU). 256 threads = 128 col-groups x 2
// row-halves; each thread: 16 rows x 8 cols, fully unrolled (32 loads in flight), s8v stores.
__global__ void prep_kernel(const float* __restrict__ x, float* __restrict__ part,
                            short* __restrict__ xbf) {
  const int b = blockIdx.x, lz = blockIdx.y;        // lz: 0..63
  const int tid = threadIdx.x;
  const int g = tid & 127, half = tid >> 7;
  const int kt = g >> 3, g8 = g & 7;
  const int mt64 = lz >> 1;
  const int rbase = (lz & 1) * 32 + half * 16;
  const float* xp = x + ((size_t)b * Lc + lz * 32 + half * 16) * Hc + g * 8;
  short* chunkbase = xbf + (((size_t)(b * 32 + mt64) * 16 + kt) << 12);
  float s[8];
  #pragma unroll
  for (int j = 0; j < 8; ++j) s[j] = 0.f;
  #pragma unroll
  for (int rr = 0; rr < 16; ++rr) {
    const int row = rbase + rr;
    f4v v0 = *reinterpret_cast<const f4v*>(xp + (size_t)rr * Hc);
    f4v v1 = *reinterpret_cast<const f4v*>(xp + (size_t)rr * Hc + 4);
    s[0] += v0[0]; s[1] += v0[1]; s[2] += v0[2]; s[3] += v0[3];
    s[4] += v1[0]; s[5] += v1[1]; s[6] += v1[2]; s[7] += v1[3];
    s8v o;
    o[0] = (short)f2bf(v0[0]); o[1] = (short)f2bf(v0[1]);
    o[2] = (short)f2bf(v0[2]); o[3] = (short)f2bf(v0[3]);
    o[4] = (short)f2bf(v1[0]); o[5] = (short)f2bf(v1[1]);
    o[6] = (short)f2bf(v1[2]); o[7] = (short)f2bf(v1[3]);
    *reinterpret_cast<s8v*>(chunkbase + row * 64 + ((g8 ^ (row & 7)) << 3)) = o;
  }
  float* pp = part + ((size_t)b * 128 + lz * 2 + half) * Hc + g * 8;
  f4v a, c;
  a[0] = s[0]; a[1] = s[1]; a[2] = s[2]; a[3] = s[3];
  c[0] = s[4]; c[1] = s[5]; c[2] = s[6]; c[3] = s[7];
  *reinterpret_cast<f4v*>(pp) = a;
  *reinterpret_cast<f4v*>(pp + 4) = c;
}

// ---------------- logits: fused z-reduce + Wr dot. grid 64 = (b,e) ----------------
__global__ void logits_kernel(const float* __restrict__ part, const float* __restrict__ Wr,
                              float* __restrict__ logits) {
  __shared__ float red[4];
  const int b = blockIdx.x >> 3, e = blockIdx.x & 7;
  const int t = threadIdx.x, lane = t & 63, wid = t >> 6;
  const int h4 = t * 4;
  f4v w = *reinterpret_cast<const f4v*>(Wr + (size_t)e * Hc + h4);
  f4v s; s[0] = 0.f; s[1] = 0.f; s[2] = 0.f; s[3] = 0.f;
  const float* pb = part + (size_t)b * 128 * Hc + h4;
  #pragma unroll 8
  for (int z = 0; z < 128; ++z) {
    f4v v = *reinterpret_cast<const f4v*>(pb + (size_t)z * Hc);
    s[0] += v[0] * w[0]; s[1] += v[1] * w[1]; s[2] += v[2] * w[2]; s[3] += v[3] * w[3];
  }
  float d = (s[0] + s[1]) + (s[2] + s[3]);
  #pragma unroll
  for (int off = 32; off > 0; off >>= 1) d += __shfl_xor(d, off);
  if (lane == 0) red[wid] = d;
  __syncthreads();
  if (t == 0) logits[blockIdx.x] = (red[0] + red[1] + red[2] + red[3]) * (1.f / (float)Lc);
}

// ---------------- inline gate: softmax + top-2 from logits (wave-uniform, deterministic) ----
__device__ __forceinline__ void compute_gate(const float* __restrict__ logits,
                                             const int* __restrict__ topk_p, int b,
                                             int* eo, float* go) {
  float v[Ec];
  float mx = -1e30f;
  #pragma unroll
  for (int e = 0; e < Ec; ++e) { v[e] = logits[b * Ec + e]; mx = fmaxf(mx, v[e]); }
  float den = 0.f;
  #pragma unroll
  for (int e = 0; e < Ec; ++e) { v[e] = expf(v[e] - mx); den += v[e]; }
  #pragma unroll
  for (int e = 0; e < Ec; ++e) v[e] /= den;
  int K = *topk_p;
  if (K > 2) K = 2;                 // pipeline supports 2 slots (bench uses top_k=2)
  float w[Ec];
  #pragma unroll
  for (int e = 0; e < Ec; ++e) w[e] = v[e];
  int prev = 0;
  for (int i = 0; i < 2; ++i) {
    if (i < K) {
      int bj = 0; float bv = w[0];
      #pragma unroll
      for (int e = 1; e < Ec; ++e) if (w[e] > bv) { bv = w[e]; bj = e; }
      go[i] = v[bj]; eo[i] = bj; w[bj] = -1.f; prev = bj;
    } else {
      go[i] = 0.f; eo[i] = prev;    // unused slot: zero gate
    }
  }
}

// ---------------- combined weight tiling: fp32 -> bf16 fragment images ----------------
__global__ void tile_weights_kernel(const float* __restrict__ Wd, const float* __restrict__ Wu,
                                    short* __restrict__ Wdt, short* __restrict__ Wut2) {
  __shared__ short t[64][264];
  const int e = blockIdx.x, y = blockIdx.y;
  const int tid = threadIdx.x;
  if (y < 16) {
    const int rt = y;
    const float* se = Wd + (size_t)e * 1024 * 256 + (size_t)(rt * 64) * 256;
    for (int idx = tid; idx < 64 * 256 / 4; idx += 256) {
      int rr = idx >> 6, c4 = (idx & 63) * 4;
      f4v v = *reinterpret_cast<const f4v*>(se + (size_t)rr * 256 + c4);
      s4v o; o[0] = (short)f2bf(v[0]); o[1] = (short)f2bf(v[1]);
      o[2] = (short)f2bf(v[2]); o[3] = (short)f2bf(v[3]);
      *reinterpret_cast<s4v*>(&t[rr][c4]) = o;
    }
    __syncthreads();
    short* de = Wdt + ((size_t)e * 16 + rt) * 16384;
    for (int gi = tid; gi < 64 * 256 / 8; gi += 256) {
      int kg = gi >> 8, c = gi & 255;
      s8v o;
      #pragma unroll
      for (int j = 0; j < 8; ++j) o[j] = t[kg * 8 + j][c];
      *reinterpret_cast<s8v*>(de + (size_t)gi * 8) = o;
    }
  } else {
    const int q = y - 16, rt = q >> 3, ct = q & 7;
    const float* se = Wu + (size_t)e * 256 * 1024 + (size_t)(rt * 64) * 1024 + ct * 128;
    for (int idx = tid; idx < 64 * 128 / 4; idx += 256) {
      int rr = idx >> 5, c4 = (idx & 31) * 4;
      f4v v = *reinterpret_cast<const f4v*>(se + (size_t)rr * 1024 + c4);
      s4v o; o[0] = (short)f2bf(v[0]); o[1] = (short)f2bf(v[1]);
      o[2] = (short)f2bf(v[2]); o[3] = (short)f2bf(v[3]);
      *reinterpret_cast<s4v*>(&t[rr][c4]) = o;
    }
    __syncthreads();
    short* de = Wut2 + ((size_t)(e * 8 + ct) * 4 + rt) * 8192;
    for (int gi = tid; gi < 64 * 128 / 8; gi += 256) {
      int kg = gi >> 7, c = gi & 127;
      s8v o;
      #pragma unroll
      for (int j = 0; j < 8; ++j) o[j] = t[kg * 8 + j][c];
      *reinterpret_cast<s8v*>(de + (size_t)gi * 8) = o;
    }
  }
}

// ---------------- GEMM1: h = g * relu(x @ Wd[e_s] + bd) -> ht (bf16, gemm2 A-image) ----------
// grid 512: bid = ((mt*2+s)*2+nt)*8 + b. 128x128 tile, K=1024, 8 waves (2x4), dbuf, 2 blocks/CU.
// Counted-vmcnt two-barrier K-loop: prefetch stays in flight across barriers (never drain mid-loop).
__global__ __launch_bounds__(512, 4) void gemm1_kernel(
    const float* __restrict__ bd, const short* __restrict__ Wdt,
    const short* __restrict__ xbf, const float* __restrict__ logits,
    const int* __restrict__ topk_p, short* __restrict__ ht) {
  __shared__ short smem[32768];   // 64KB: A bufs at 0/8192, B bufs at 16384/24576 (shorts)

  const int bid = blockIdx.x;
  const int b = bid & 7, q = bid >> 3;       // q: 0..63
  const int nt = q & 1, s = (q >> 1) & 1, mt = q >> 2;   // mt: 0..15 (128-row tiles)
  int esel[2]; float gsel[2];
  compute_gate(logits, topk_p, b, esel, gsel);   // fully consumed before staging (addresses)
  const int e = esel[s];
  const float g = gsel[s];
  const int tid = threadIdx.x, lane = tid & 63, wid = tid >> 6;
  const int wr = wid >> 2, wc = wid & 3, lr = lane & 15, lg = lane >> 4;
  const short* wdt = Wdt + (size_t)e * (Rc * Hc);
  const size_t xc0 = ((size_t)(b * 32 + mt * 2) * 16) << 12;
  const size_t xc1 = ((size_t)(b * 32 + mt * 2 + 1) * 16) << 12;
  const int bkg0 = tid >> 7, bc0 = tid & 127;
  const int bkg1 = (512 + tid) >> 7, bc1 = (512 + tid) & 127;

  f4v acc[4][2];
  #pragma unroll
  for (int m = 0; m < 4; ++m)
    #pragma unroll
    for (int n = 0; n < 2; ++n) { acc[m][n][0]=0.f; acc[m][n][1]=0.f; acc[m][n][2]=0.f; acc[m][n][3]=0.f; }

  // prologue: stage kt=0 (exactly 4 VMEM ops/thread; nothing else touches vmcnt in the loop)
  gload_lds16(xbf + xc0 + tid * 8, &smem[tid * 8]);
  gload_lds16(xbf + xc1 + tid * 8, &smem[4096 + tid * 8]);
  gload_lds16(wdt + bkg0 * 2048 + nt * 1024 + bc0 * 8, &smem[16384 + tid * 8]);
  gload_lds16(wdt + bkg1 * 2048 + nt * 1024 + bc1 * 8, &smem[16384 + 4096 + tid * 8]);

  for (int kt = 0; kt < 16; ++kt) {
    const int cur = kt & 1, nxt = cur ^ 1;
    if (kt < 15) {
      const size_t ko = (size_t)(kt + 1) << 12;
      const short* wsrc = wdt + (kt + 1) * 16384;
      gload_lds16(xbf + xc0 + ko + tid * 8, &smem[nxt * 8192 + tid * 8]);
      gload_lds16(xbf + xc1 + ko + tid * 8, &smem[nxt * 8192 + 4096 + tid * 8]);
      gload_lds16(wsrc + bkg0 * 2048 + nt * 1024 + bc0 * 8, &smem[16384 + nxt * 8192 + tid * 8]);
      gload_lds16(wsrc + bkg1 * 2048 + nt * 1024 + bc1 * 8, &smem[16384 + nxt * 8192 + 4096 + tid * 8]);
      asm volatile("s_waitcnt vmcnt(4)" ::: "memory");   // cur's 4 done; nxt's 4 stay in flight
    } else {
      asm volatile("s_waitcnt vmcnt(0)" ::: "memory");   // last tile: full drain
    }
    __builtin_amdgcn_s_barrier();                        // cur ready for all waves
    #pragma unroll
    for (int kk = 0; kk < 2; ++kk) {
      const int kg = kk * 4 + lg;
      s8v af[4], bf[2];
      #pragma unroll
      for (int m = 0; m < 4; ++m) {
        int r = wr * 64 + m * 16 + lr;
        af[m] = *reinterpret_cast<const s8v*>(
            &smem[cur * 8192 + (r >> 6) * 4096 + (r & 63) * 64 + ((kg ^ (r & 7)) << 3)]);
      }
      #pragma unroll
      for (int n = 0; n < 2; ++n) {
        int c = wc * 32 + n * 16 + lr;
        bf[n] = *reinterpret_cast<const s8v*>(&smem[16384 + cur * 8192 + (kg * 128 + c) * 8]);
      }
      #pragma unroll
      for (int m = 0; m < 4; ++m)
        #pragma unroll
        for (int n = 0; n < 2; ++n)
          acc[m][n] = __builtin_amdgcn_mfma_f32_16x16x32_bf16(af[m], bf[n], acc[m][n], 0, 0, 0);
    }
    __builtin_amdgcn_s_barrier();                        // all waves done reading cur
  }

  // epilogue: bias + relu + gate -> LDS bounce in ht image -> contiguous 32KB blast
  short* rp = smem;
  const float* bde = bd + e * Rc + nt * 128;
  #pragma unroll
  for (int n = 0; n < 2; ++n) {
    int c = wc * 32 + n * 16 + lr;
    float bdv = bde[c];
    int d = c >> 6, kg = (c >> 3) & 7, j = c & 7;
    #pragma unroll
    for (int m = 0; m < 4; ++m)
      #pragma unroll
      for (int i = 0; i < 4; ++i) {
        int r = wr * 64 + m * 16 + lg * 4 + i;
        float vv = fmaxf(acc[m][n][i] + bdv, 0.f) * g;
        rp[((d * 8 + kg) * 128 + r) * 8 + j] = (short)f2bf(vv);
      }
  }
  __syncthreads();
  short* hb = ht + (((size_t)(b * 16 + mt) * 8) + s * 4 + nt * 2) * 8192;
  #pragma unroll
  for (int p = 0; p < 4; ++p) {
    int gi = p * 512 + tid;
    *reinterpret_cast<s8v*>(hb + (size_t)gi * 8) = *reinterpret_cast<const s8v*>(&rp[gi * 8]);
  }
}

// ---------------- GEMM2: out = x + h_concat @ Wu_concat + sum g*bu ----------------
// grid 1024: bid = (mt2*8+nt)*8 + b. 128x128 tile, K=512 (2 experts concat), dbuf, 2 blocks/CU.
// Counted-vmcnt two-barrier K-loop, same schedule as GEMM1.
__global__ __launch_bounds__(512, 4) void gemm2_kernel(
    const float* __restrict__ x, const float* __restrict__ bu,
    const short* __restrict__ ht, const short* __restrict__ Wut2,
    const float* __restrict__ logits, const int* __restrict__ topk_p,
    float* __restrict__ out) {
  __shared__ short smem[32768];   // 64KB: A bufs at 0/8192, B at 16384/24576 (shorts)

  const int bid = blockIdx.x;
  const int b = bid & 7, q = bid >> 3;
  const int mt2 = q >> 3, nt = q & 7;
  int esel[2]; float gsel[2];
  compute_gate(logits, topk_p, b, esel, gsel);   // consumed before staging
  const int e0 = esel[0], e1 = esel[1];
  const float g0 = gsel[0], g1 = gsel[1];
  const int tid = threadIdx.x, lane = tid & 63, wid = tid >> 6;
  const int wr = wid >> 2, wc = wid & 3, lr = lane & 15, lg = lane >> 4;
  const short* ab = ht + ((size_t)b * 16 + mt2) * 65536;

  f4v acc[4][2];
  #pragma unroll
  for (int m = 0; m < 4; ++m)
    #pragma unroll
    for (int n = 0; n < 2; ++n) { acc[m][n][0]=0.f; acc[m][n][1]=0.f; acc[m][n][2]=0.f; acc[m][n][3]=0.f; }

  // prologue: stage ft=0 (4 VMEM ops/thread)
  {
    const short* gb = Wut2 + (((size_t)e0 * 8 + nt) * 4 + 0) * 8192;
    #pragma unroll
    for (int p = 0; p < 2; ++p) {
      gload_lds16(ab + (p * 512 + tid) * 8, &smem[(p * 512 + tid) * 8]);
      gload_lds16(gb + (p * 512 + tid) * 8, &smem[16384 + (p * 512 + tid) * 8]);
    }
  }

  for (int ft = 0; ft < 8; ++ft) {
    const int cur = ft & 1, nxt = cur ^ 1;
    if (ft < 7) {
      const int f2 = ft + 1;
      const short* ga = ab + f2 * 8192;
      const int ee = (f2 < 4) ? e0 : e1;
      const short* gb = Wut2 + (((size_t)ee * 8 + nt) * 4 + (f2 & 3)) * 8192;
      #pragma unroll
      for (int p = 0; p < 2; ++p) {
        gload_lds16(ga + (p * 512 + tid) * 8, &smem[nxt * 8192 + (p * 512 + tid) * 8]);
        gload_lds16(gb + (p * 512 + tid) * 8, &smem[16384 + nxt * 8192 + (p * 512 + tid) * 8]);
      }
      asm volatile("s_waitcnt vmcnt(4)" ::: "memory");   // cur ready; next tile in flight
    } else {
      asm volatile("s_waitcnt vmcnt(0)" ::: "memory");
    }
    __builtin_amdgcn_s_barrier();
    #pragma unroll
    for (int kk = 0; kk < 2; ++kk) {
      s8v af[4], bf[2];
      #pragma unroll
      for (int m = 0; m < 4; ++m) {
        int r = wr * 64 + m * 16 + lr;
        af[m] = *reinterpret_cast<const s8v*>(&smem[cur * 8192 + ((kk * 4 + lg) * 128 + r) * 8]);
      }
      #pragma unroll
      for (int n = 0; n < 2; ++n) {
        int c = wc * 32 + n * 16 + lr;
        bf[n] = *reinterpret_cast<const s8v*>(&smem[16384 + cur * 8192 + ((kk * 4 + lg) * 128 + c) * 8]);
      }
      #pragma unroll
      for (int m = 0; m < 4; ++m)
        #pragma unroll
        for (int n = 0; n < 2; ++n)
          acc[m][n] = __builtin_amdgcn_mfma_f32_16x16x32_bf16(af[m], bf[n], acc[m][n], 0, 0, 0);
    }
    __builtin_amdgcn_s_barrier();
  }

  // epilogue: LDS f32 bounce (swizzled) -> coalesced residual + gated-bias + dwordx4 stores
  float* lf = (float*)smem;   // 128x128 f32 = 64KB
  #pragma unroll
  for (int n = 0; n < 2; ++n) {
    int C = wc * 32 + n * 16 + lr;
    #pragma unroll
    for (int m = 0; m < 4; ++m)
      #pragma unroll
      for (int i = 0; i < 4; ++i) {
        int R = wr * 64 + m * 16 + lg * 4 + i;
        lf[R * 128 + ((((C >> 2) ^ (R & 7)) << 2) | (C & 3))] = acc[m][n][i];
      }
  }
  __syncthreads();
  {
    const int r = tid >> 2, cq = tid & 3;
    const int Rg = mt2 * 128 + r, Cbase = nt * 128;
    const float* xrow = x + ((size_t)b * Lc + Rg) * Hc + Cbase;
    float* orow = out + ((size_t)b * Lc + Rg) * Hc + Cbase;
    const float* bu0 = bu + (size_t)e0 * Hc + Cbase;
    const float* bu1 = bu + (size_t)e1 * Hc + Cbase;
    #pragma unroll
    for (int k = 0; k < 8; ++k) {
      int c = k * 16 + cq * 4;
      int c4 = (c >> 2) ^ (r & 7);
      f4v v = *reinterpret_cast<const f4v*>(&lf[r * 128 + (c4 << 2)]);
      f4v xv = *reinterpret_cast<const f4v*>(xrow + c);
      f4v b0 = *reinterpret_cast<const f4v*>(bu0 + c);
      f4v b1 = *reinterpret_cast<const f4v*>(bu1 + c);
      f4v o;
      #pragma unroll
      for (int j = 0; j < 4; ++j) o[j] = xv[j] + v[j] + g0 * b0[j] + g1 * b1[j];
      *reinterpret_cast<f4v*>(orow + c) = o;
    }
  }
}

extern "C" void kernel_launch(void* const* d_in, const int* in_sizes, int n_in,
                              void* d_out, int out_size, void* d_ws, size_t ws_size,
                              hipStream_t stream) {
  const float* x  = (const float*)d_in[0];
  const float* Wd = (const float*)d_in[1];
  const float* bd = (const float*)d_in[2];
  const float* Wu = (const float*)d_in[3];
  const float* bu = (const float*)d_in[4];
  const float* Wr = (const float*)d_in[5];
  const int* topk = (const int*)d_in[6];
  float* out = (float*)d_out;

  char* ws = (char*)d_ws;
  float* logits = (float*)ws;                              // 256 B
  float* part   = (float*)(ws + 65536);                    // (B,128,H) f32, 4 MB
  char*  p1     = ws + 65536 + (size_t)Bc * 128 * Hc * 4;
  short* Wdt    = (short*)p1;                              // 4 MB  (tiled)
  short* Wut2   = (short*)(p1 + (size_t)Ec * Hc * Rc * 2); // 4 MB (tiled)
  short* ht     = (short*)(p1 + (size_t)Ec * Hc * Rc * 4); // 16 MB (B*L*512 bf16, tiled)
  short* xbf    = (short*)(p1 + (size_t)Ec * Hc * Rc * 4 + (size_t)Bc * Lc * 512 * 2); // 32 MB

  hipLaunchKernelGGL(prep_kernel, dim3(Bc, 64), dim3(256), 0, stream, x, part, xbf);
  hipLaunchKernelGGL(tile_weights_kernel, dim3(Ec, 48), dim3(256), 0, stream,
                     Wd, Wu, Wdt, Wut2);
  hipLaunchKernelGGL(logits_kernel, dim3(Bc * Ec), dim3(256), 0, stream, part, Wr, logits);
  hipLaunchKernelGGL(gemm1_kernel, dim3(512), dim3(512), 0, stream,
                     bd, Wdt, xbf, logits, topk, ht);
  hipLaunchKernelGGL(gemm2_kernel, dim3(1024), dim3(512), 0, stream,
                     x, bu, ht, Wut2, logits, topk, out);
}

// Round 11
// 94.767 us; speedup vs baseline: 1.0221x; 1.0221x over previous
//
#include <hip/hip_runtime.h>
#include <hip/hip_bf16.h>

// MoE adapter: out = x + sum_{e in top2} g_e * (relu(x@Wd[e]+bd[e]) @ Wu[e] + bu[e])
// B=8, L=2048, H=1024, E=8, R=256, top_k=2 (pipeline supports up to 2 slots).
// prep(pool + x->bf16 A-image) -> tiled bf16 weights -> GEMM1 (h, gate-folded) -> GEMM2 (+residual).
// GEMM2: K-step 32, 32KB LDS, 4 blocks/CU, counted-vmcnt; residual from bf16 x-image.

typedef __attribute__((ext_vector_type(8))) short s8v;
typedef __attribute__((ext_vector_type(4))) short s4v;
typedef __attribute__((ext_vector_type(4))) float f4v;

constexpr int Bc = 8, Lc = 2048, Hc = 1024, Ec = 8, Rc = 256;

__device__ __forceinline__ unsigned short f2bf(float f) {
  unsigned int u = __float_as_uint(f);
  u += 0x7fffu + ((u >> 16) & 1u);   // RNE
  return (unsigned short)(u >> 16);
}
__device__ __forceinline__ float bf2f(unsigned short u) {
  return __uint_as_float((unsigned int)u << 16);
}

typedef __attribute__((address_space(1))) const unsigned int ga_u32;
typedef __attribute__((address_space(3))) unsigned int ls_u32;
__device__ __forceinline__ void gload_lds16(const void* g, void* l) {
  __builtin_amdgcn_global_load_lds((ga_u32*)g, (ls_u32*)l, 16, 0, 0);
}

// ---------------- prep: pool partials + x -> bf16 in gemm1 A-image layout ----------------
__global__ void prep_kernel(const float* __restrict__ x, float* __restrict__ part,
                            short* __restrict__ xbf) {
  const int b = blockIdx.x, lz = blockIdx.y;        // lz: 0..63
  const int tid = threadIdx.x;
  const int g = tid & 127, half = tid >> 7;
  const int kt = g >> 3, g8 = g & 7;
  const int mt64 = lz >> 1;
  const int rbase = (lz & 1) * 32 + half * 16;
  const float* xp = x + ((size_t)b * Lc + lz * 32 + half * 16) * Hc + g * 8;
  short* chunkbase = xbf + (((size_t)(b * 32 + mt64) * 16 + kt) << 12);
  float s[8];
  #pragma unroll
  for (int j = 0; j < 8; ++j) s[j] = 0.f;
  #pragma unroll
  for (int rr = 0; rr < 16; ++rr) {
    const int row = rbase + rr;
    f4v v0 = *reinterpret_cast<const f4v*>(xp + (size_t)rr * Hc);
    f4v v1 = *reinterpret_cast<const f4v*>(xp + (size_t)rr * Hc + 4);
    s[0] += v0[0]; s[1] += v0[1]; s[2] += v0[2]; s[3] += v0[3];
    s[4] += v1[0]; s[5] += v1[1]; s[6] += v1[2]; s[7] += v1[3];
    s8v o;
    o[0] = (short)f2bf(v0[0]); o[1] = (short)f2bf(v0[1]);
    o[2] = (short)f2bf(v0[2]); o[3] = (short)f2bf(v0[3]);
    o[4] = (short)f2bf(v1[0]); o[5] = (short)f2bf(v1[1]);
    o[6] = (short)f2bf(v1[2]); o[7] = (short)f2bf(v1[3]);
    *reinterpret_cast<s8v*>(chunkbase + row * 64 + ((g8 ^ (row & 7)) << 3)) = o;
  }
  float* pp = part + ((size_t)b * 128 + lz * 2 + half) * Hc + g * 8;
  f4v a, c;
  a[0] = s[0]; a[1] = s[1]; a[2] = s[2]; a[3] = s[3];
  c[0] = s[4]; c[1] = s[5]; c[2] = s[6]; c[3] = s[7];
  *reinterpret_cast<f4v*>(pp) = a;
  *reinterpret_cast<f4v*>(pp + 4) = c;
}

// ---------------- logits: fused z-reduce + Wr dot. grid 64 = (b,e) ----------------
__global__ void logits_kernel(const float* __restrict__ part, const float* __restrict__ Wr,
                              float* __restrict__ logits) {
  __shared__ float red[4];
  const int b = blockIdx.x >> 3, e = blockIdx.x & 7;
  const int t = threadIdx.x, lane = t & 63, wid = t >> 6;
  const int h4 = t * 4;
  f4v w = *reinterpret_cast<const f4v*>(Wr + (size_t)e * Hc + h4);
  f4v s; s[0] = 0.f; s[1] = 0.f; s[2] = 0.f; s[3] = 0.f;
  const float* pb = part + (size_t)b * 128 * Hc + h4;
  #pragma unroll 8
  for (int z = 0; z < 128; ++z) {
    f4v v = *reinterpret_cast<const f4v*>(pb + (size_t)z * Hc);
    s[0] += v[0] * w[0]; s[1] += v[1] * w[1]; s[2] += v[2] * w[2]; s[3] += v[3] * w[3];
  }
  float d = (s[0] + s[1]) + (s[2] + s[3]);
  #pragma unroll
  for (int off = 32; off > 0; off >>= 1) d += __shfl_xor(d, off);
  if (lane == 0) red[wid] = d;
  __syncthreads();
  if (t == 0) logits[blockIdx.x] = (red[0] + red[1] + red[2] + red[3]) * (1.f / (float)Lc);
}

// ---------------- inline gate: softmax + top-2 from logits (wave-uniform, deterministic) ----
__device__ __forceinline__ void compute_gate(const float* __restrict__ logits,
                                             const int* __restrict__ topk_p, int b,
                                             int* eo, float* go) {
  float v[Ec];
  float mx = -1e30f;
  #pragma unroll
  for (int e = 0; e < Ec; ++e) { v[e] = logits[b * Ec + e]; mx = fmaxf(mx, v[e]); }
  float den = 0.f;
  #pragma unroll
  for (int e = 0; e < Ec; ++e) { v[e] = expf(v[e] - mx); den += v[e]; }
  #pragma unroll
  for (int e = 0; e < Ec; ++e) v[e] /= den;
  int K = *topk_p;
  if (K > 2) K = 2;                 // pipeline supports 2 slots (bench uses top_k=2)
  float w[Ec];
  #pragma unroll
  for (int e = 0; e < Ec; ++e) w[e] = v[e];
  int prev = 0;
  for (int i = 0; i < 2; ++i) {
    if (i < K) {
      int bj = 0; float bv = w[0];
      #pragma unroll
      for (int e = 1; e < Ec; ++e) if (w[e] > bv) { bv = w[e]; bj = e; }
      go[i] = v[bj]; eo[i] = bj; w[bj] = -1.f; prev = bj;
    } else {
      go[i] = 0.f; eo[i] = prev;    // unused slot: zero gate
    }
  }
}

// ---------------- combined weight tiling: fp32 -> bf16 fragment images ----------------
__global__ void tile_weights_kernel(const float* __restrict__ Wd, const float* __restrict__ Wu,
                                    short* __restrict__ Wdt, short* __restrict__ Wut2) {
  __shared__ short t[64][264];
  const int e = blockIdx.x, y = blockIdx.y;
  const int tid = threadIdx.x;
  if (y < 16) {
    const int rt = y;
    const float* se = Wd + (size_t)e * 1024 * 256 + (size_t)(rt * 64) * 256;
    for (int idx = tid; idx < 64 * 256 / 4; idx += 256) {
      int rr = idx >> 6, c4 = (idx & 63) * 4;
      f4v v = *reinterpret_cast<const f4v*>(se + (size_t)rr * 256 + c4);
      s4v o; o[0] = (short)f2bf(v[0]); o[1] = (short)f2bf(v[1]);
      o[2] = (short)f2bf(v[2]); o[3] = (short)f2bf(v[3]);
      *reinterpret_cast<s4v*>(&t[rr][c4]) = o;
    }
    __syncthreads();
    short* de = Wdt + ((size_t)e * 16 + rt) * 16384;
    for (int gi = tid; gi < 64 * 256 / 8; gi += 256) {
      int kg = gi >> 8, c = gi & 255;
      s8v o;
      #pragma unroll
      for (int j = 0; j < 8; ++j) o[j] = t[kg * 8 + j][c];
      *reinterpret_cast<s8v*>(de + (size_t)gi * 8) = o;
    }
  } else {
    const int q = y - 16, rt = q >> 3, ct = q & 7;
    const float* se = Wu + (size_t)e * 256 * 1024 + (size_t)(rt * 64) * 1024 + ct * 128;
    for (int idx = tid; idx < 64 * 128 / 4; idx += 256) {
      int rr = idx >> 5, c4 = (idx & 31) * 4;
      f4v v = *reinterpret_cast<const f4v*>(se + (size_t)rr * 1024 + c4);
      s4v o; o[0] = (short)f2bf(v[0]); o[1] = (short)f2bf(v[1]);
      o[2] = (short)f2bf(v[2]); o[3] = (short)f2bf(v[3]);
      *reinterpret_cast<s4v*>(&t[rr][c4]) = o;
    }
    __syncthreads();
    short* de = Wut2 + ((size_t)(e * 8 + ct) * 4 + rt) * 8192;
    for (int gi = tid; gi < 64 * 128 / 8; gi += 256) {
      int kg = gi >> 7, c = gi & 127;
      s8v o;
      #pragma unroll
      for (int j = 0; j < 8; ++j) o[j] = t[kg * 8 + j][c];
      *reinterpret_cast<s8v*>(de + (size_t)gi * 8) = o;
    }
  }
}

// ---------------- GEMM1: h = g * relu(x @ Wd[e_s] + bd) -> ht (bf16, gemm2 A-image) ----------
// grid 512: bid = ((mt*2+s)*2+nt)*8 + b. 128x128 tile, K=1024, 8 waves (2x4), dbuf, 2 blocks/CU.
__global__ __launch_bounds__(512, 4) void gemm1_kernel(
    const float* __restrict__ bd, const short* __restrict__ Wdt,
    const short* __restrict__ xbf, const float* __restrict__ logits,
    const int* __restrict__ topk_p, short* __restrict__ ht) {
  __shared__ short smem[32768];   // 64KB: A bufs at 0/8192, B bufs at 16384/24576 (shorts)

  const int bid = blockIdx.x;
  const int b = bid & 7, q = bid >> 3;       // q: 0..63
  const int nt = q & 1, s = (q >> 1) & 1, mt = q >> 2;   // mt: 0..15 (128-row tiles)
  int esel[2]; float gsel[2];
  compute_gate(logits, topk_p, b, esel, gsel);
  const int e = esel[s];
  const float g = gsel[s];
  const int tid = threadIdx.x, lane = tid & 63, wid = tid >> 6;
  const int wr = wid >> 2, wc = wid & 3, lr = lane & 15, lg = lane >> 4;
  const short* wdt = Wdt + (size_t)e * (Rc * Hc);
  const size_t xc0 = ((size_t)(b * 32 + mt * 2) * 16) << 12;
  const size_t xc1 = ((size_t)(b * 32 + mt * 2 + 1) * 16) << 12;
  const int bkg0 = tid >> 7, bc0 = tid & 127;
  const int bkg1 = (512 + tid) >> 7, bc1 = (512 + tid) & 127;

  f4v acc[4][2];
  #pragma unroll
  for (int m = 0; m < 4; ++m)
    #pragma unroll
    for (int n = 0; n < 2; ++n) { acc[m][n][0]=0.f; acc[m][n][1]=0.f; acc[m][n][2]=0.f; acc[m][n][3]=0.f; }

  // prologue: stage kt=0 (exactly 4 VMEM ops/thread)
  gload_lds16(xbf + xc0 + tid * 8, &smem[tid * 8]);
  gload_lds16(xbf + xc1 + tid * 8, &smem[4096 + tid * 8]);
  gload_lds16(wdt + bkg0 * 2048 + nt * 1024 + bc0 * 8, &smem[16384 + tid * 8]);
  gload_lds16(wdt + bkg1 * 2048 + nt * 1024 + bc1 * 8, &smem[16384 + 4096 + tid * 8]);

  for (int kt = 0; kt < 16; ++kt) {
    const int cur = kt & 1, nxt = cur ^ 1;
    if (kt < 15) {
      const size_t ko = (size_t)(kt + 1) << 12;
      const short* wsrc = wdt + (kt + 1) * 16384;
      gload_lds16(xbf + xc0 + ko + tid * 8, &smem[nxt * 8192 + tid * 8]);
      gload_lds16(xbf + xc1 + ko + tid * 8, &smem[nxt * 8192 + 4096 + tid * 8]);
      gload_lds16(wsrc + bkg0 * 2048 + nt * 1024 + bc0 * 8, &smem[16384 + nxt * 8192 + tid * 8]);
      gload_lds16(wsrc + bkg1 * 2048 + nt * 1024 + bc1 * 8, &smem[16384 + nxt * 8192 + 4096 + tid * 8]);
      asm volatile("s_waitcnt vmcnt(4)" ::: "memory");
    } else {
      asm volatile("s_waitcnt vmcnt(0)" ::: "memory");
    }
    __builtin_amdgcn_s_barrier();
    #pragma unroll
    for (int kk = 0; kk < 2; ++kk) {
      const int kg = kk * 4 + lg;
      s8v af[4], bf[2];
      #pragma unroll
      for (int m = 0; m < 4; ++m) {
        int r = wr * 64 + m * 16 + lr;
        af[m] = *reinterpret_cast<const s8v*>(
            &smem[cur * 8192 + (r >> 6) * 4096 + (r & 63) * 64 + ((kg ^ (r & 7)) << 3)]);
      }
      #pragma unroll
      for (int n = 0; n < 2; ++n) {
        int c = wc * 32 + n * 16 + lr;
        bf[n] = *reinterpret_cast<const s8v*>(&smem[16384 + cur * 8192 + (kg * 128 + c) * 8]);
      }
      #pragma unroll
      for (int m = 0; m < 4; ++m)
        #pragma unroll
        for (int n = 0; n < 2; ++n)
          acc[m][n] = __builtin_amdgcn_mfma_f32_16x16x32_bf16(af[m], bf[n], acc[m][n], 0, 0, 0);
    }
    __builtin_amdgcn_s_barrier();
  }

  // epilogue: bias + relu + gate -> LDS bounce in ht image -> contiguous 32KB blast
  short* rp = smem;
  const float* bde = bd + e * Rc + nt * 128;
  #pragma unroll
  for (int n = 0; n < 2; ++n) {
    int c = wc * 32 + n * 16 + lr;
    float bdv = bde[c];
    int d = c >> 6, kg = (c >> 3) & 7, j = c & 7;
    #pragma unroll
    for (int m = 0; m < 4; ++m)
      #pragma unroll
      for (int i = 0; i < 4; ++i) {
        int r = wr * 64 + m * 16 + lg * 4 + i;
        float vv = fmaxf(acc[m][n][i] + bdv, 0.f) * g;
        rp[((d * 8 + kg) * 128 + r) * 8 + j] = (short)f2bf(vv);
      }
  }
  __syncthreads();
  short* hb = ht + (((size_t)(b * 16 + mt) * 8) + s * 4 + nt * 2) * 8192;
  #pragma unroll
  for (int p = 0; p < 4; ++p) {
    int gi = p * 512 + tid;
    *reinterpret_cast<s8v*>(hb + (size_t)gi * 8) = *reinterpret_cast<const s8v*>(&rp[gi * 8]);
  }
}

// ---------------- GEMM2: out = bf16(x) + h_concat @ Wu_concat + sum g*bu ----------------
// grid 1024: bid = (mt2*8+nt)*8 + b. 128x128 tile, K-step 32 (16 steps over 2-expert concat
// K=512), 32KB LDS dbuf -> 4 blocks/CU, counted vmcnt(2). Residual read from xbf (bf16).
__global__ __launch_bounds__(512, 8) void gemm2_kernel(
    const short* __restrict__ xbf, const float* __restrict__ bu,
    const short* __restrict__ ht, const short* __restrict__ Wut2,
    const float* __restrict__ logits, const int* __restrict__ topk_p,
    float* __restrict__ out) {
  __shared__ short smem[16384];   // 32KB: A bufs at 0/4096, B bufs at 8192/12288 (shorts)

  const int bid = blockIdx.x;
  const int b = bid & 7, q = bid >> 3;
  const int mt2 = q >> 3, nt = q & 7;
  int esel[2]; float gsel[2];
  compute_gate(logits, topk_p, b, esel, gsel);
  const int e0 = esel[0], e1 = esel[1];
  const float g0 = gsel[0], g1 = gsel[1];
  const int tid = threadIdx.x, lane = tid & 63, wid = tid >> 6;
  const int wr = wid >> 2, wc = wid & 3, lr = lane & 15, lg = lane >> 4;
  const short* ab = ht + ((size_t)b * 16 + mt2) * 65536;

  f4v acc[4][2];
  #pragma unroll
  for (int m = 0; m < 4; ++m)
    #pragma unroll
    for (int n = 0; n < 2; ++n) { acc[m][n][0]=0.f; acc[m][n][1]=0.f; acc[m][n][2]=0.f; acc[m][n][3]=0.f; }

  // prologue: stage fts=0 (2 VMEM ops/thread; kg 0..3 of ft 0 = first 4096 shorts)
  gload_lds16(ab + tid * 8, &smem[tid * 8]);
  gload_lds16(Wut2 + ((size_t)e0 * 8 + nt) * 4 * 8192 + tid * 8, &smem[8192 + tid * 8]);

  for (int fts = 0; fts < 16; ++fts) {           // 16 half-K steps (K=32 each)
    const int cur = fts & 1, nxt = cur ^ 1;
    if (fts < 15) {
      const int f2 = fts + 1;
      const short* ga = ab + (f2 >> 1) * 8192 + (f2 & 1) * 4096;
      const int ee = (f2 < 8) ? e0 : e1;
      const short* gb = Wut2 + (((size_t)ee * 8 + nt) * 4 + ((f2 >> 1) & 3)) * 8192 + (f2 & 1) * 4096;
      gload_lds16(ga + tid * 8, &smem[nxt * 4096 + tid * 8]);
      gload_lds16(gb + tid * 8, &smem[8192 + nxt * 4096 + tid * 8]);
      asm volatile("s_waitcnt vmcnt(2)" ::: "memory");   // cur ready; nxt stays in flight
    } else {
      asm volatile("s_waitcnt vmcnt(0)" ::: "memory");
    }
    __builtin_amdgcn_s_barrier();
    {
      s8v af[4], bf[2];
      #pragma unroll
      for (int m = 0; m < 4; ++m) {
        int r = wr * 64 + m * 16 + lr;
        af[m] = *reinterpret_cast<const s8v*>(&smem[cur * 4096 + (lg * 128 + r) * 8]);
      }
      #pragma unroll
      for (int n = 0; n < 2; ++n) {
        int c = wc * 32 + n * 16 + lr;
        bf[n] = *reinterpret_cast<const s8v*>(&smem[8192 + cur * 4096 + (lg * 128 + c) * 8]);
      }
      #pragma unroll
      for (int m = 0; m < 4; ++m)
        #pragma unroll
        for (int n = 0; n < 2; ++n)
          acc[m][n] = __builtin_amdgcn_mfma_f32_16x16x32_bf16(af[m], bf[n], acc[m][n], 0, 0, 0);
    }
    __builtin_amdgcn_s_barrier();
  }

  // epilogue: acc -> bf16 LDS bounce (XOR swizzle) -> residual(bf16 x-image) + gated bias
  short* lb = smem;   // 128x128 bf16 = 16384 shorts, exactly fits
  #pragma unroll
  for (int n = 0; n < 2; ++n) {
    int C = wc * 32 + n * 16 + lr;
    #pragma unroll
    for (int m = 0; m < 4; ++m)
      #pragma unroll
      for (int i = 0; i < 4; ++i) {
        int R = wr * 64 + m * 16 + lg * 4 + i;
        lb[R * 128 + (C ^ ((R & 7) << 4))] = (short)f2bf(acc[m][n][i]);
      }
  }
  __syncthreads();
  {
    const int r = tid >> 2, cq = tid & 3;
    const int Rg = mt2 * 128 + r, Cbase = nt * 128;
    float* orow = out + ((size_t)b * Lc + Rg) * Hc + Cbase;
    const float* bu0 = bu + (size_t)e0 * Hc + Cbase;
    const float* bu1 = bu + (size_t)e1 * Hc + Cbase;
    // xbf chunk base for this row: chunk (b, Rg>>6, kt), within-chunk row = r&63
    const short* xrow = xbf + ((size_t)(b * 32 + (Rg >> 6)) * 16) * 4096 + (r & 63) * 64;
    #pragma unroll
    for (int k = 0; k < 8; ++k) {
      int c = k * 16 + cq * 4;       // block-local col, 4-aligned
      int C = Cbase + c;             // global col
      const short* xp = xrow + (C >> 6) * 4096 + ((((C >> 3) & 7) ^ (r & 7)) << 3) + (C & 7);
      s4v xv = *reinterpret_cast<const s4v*>(xp);
      s4v av = *reinterpret_cast<const s4v*>(&lb[r * 128 + (c ^ ((r & 7) << 4))]);
      f4v bv0 = *reinterpret_cast<const f4v*>(bu0 + c);
      f4v bv1 = *reinterpret_cast<const f4v*>(bu1 + c);
      f4v o;
      #pragma unroll
      for (int j = 0; j < 4; ++j)
        o[j] = bf2f((unsigned short)xv[j]) + bf2f((unsigned short)av[j])
             + g0 * bv0[j] + g1 * bv1[j];
      *reinterpret_cast<f4v*>(orow + c) = o;
    }
  }
}

extern "C" void kernel_launch(void* const* d_in, const int* in_sizes, int n_in,
                              void* d_out, int out_size, void* d_ws, size_t ws_size,
                              hipStream_t stream) {
  const float* x  = (const float*)d_in[0];
  const float* Wd = (const float*)d_in[1];
  const float* bd = (const float*)d_in[2];
  const float* Wu = (const float*)d_in[3];
  const float* bu = (const float*)d_in[4];
  const float* Wr = (const float*)d_in[5];
  const int* topk = (const int*)d_in[6];
  float* out = (float*)d_out;

  char* ws = (char*)d_ws;
  float* logits = (float*)ws;                              // 256 B
  float* part   = (float*)(ws + 65536);                    // (B,128,H) f32, 4 MB
  char*  p1     = ws + 65536 + (size_t)Bc * 128 * Hc * 4;
  short* Wdt    = (short*)p1;                              // 4 MB  (tiled)
  short* Wut2   = (short*)(p1 + (size_t)Ec * Hc * Rc * 2); // 4 MB (tiled)
  short* ht     = (short*)(p1 + (size_t)Ec * Hc * Rc * 4); // 16 MB (B*L*512 bf16, tiled)
  short* xbf    = (short*)(p1 + (size_t)Ec * Hc * Rc * 4 + (size_t)Bc * Lc * 512 * 2); // 32 MB

  hipLaunchKernelGGL(prep_kernel, dim3(Bc, 64), dim3(256), 0, stream, x, part, xbf);
  hipLaunchKernelGGL(tile_weights_kernel, dim3(Ec, 48), dim3(256), 0, stream,
                     Wd, Wu, Wdt, Wut2);
  hipLaunchKernelGGL(logits_kernel, dim3(Bc * Ec), dim3(256), 0, stream, part, Wr, logits);
  hipLaunchKernelGGL(gemm1_kernel, dim3(512), dim3(512), 0, stream,
                     bd, Wdt, xbf, logits, topk, ht);
  hipLaunchKernelGGL(gemm2_kernel, dim3(1024), dim3(512), 0, stream,
                     xbf, bu, ht, Wut2, logits, topk, out);
}